// Round 1
// baseline (1010.819 us; speedup 1.0000x reference)
//
#include <hip/hip_runtime.h>

#define NUM_FRAME 300
#define LEN_FRAME 512
#define T_LEN     20000
#define NUM_BC    200   // 4*50

// Hann-windowed circular autocorrelation, normalized, first 256 lags,
// mean over the 2 interleaved channels.
// One block per (bc, frame). 128 threads = 2 waves; wave = one channel.
__global__ __launch_bounds__(128) void acorr_kernel(const float* __restrict__ in,
                                                    float* __restrict__ out) {
    const int bid   = blockIdx.x;          // 0 .. 60000-1
    const int bc    = bid / NUM_FRAME;
    const int frame = bid - bc * NUM_FRAME;

    // starts = np.linspace(0, 19488, 300).astype(int64): y[i] = i*(19488/299.) in
    // double, y[-1] set exactly to 19488. Min fractional part is 1/299 so trunc
    // is safe against double rounding.
    int start;
    if (frame == NUM_FRAME - 1) start = T_LEN - LEN_FRAME;
    else start = (int)((double)frame *
                       ((double)(T_LEN - LEN_FRAME) / (double)(NUM_FRAME - 1)));

    // windowed frame per channel, with 256-float circular duplicate (need idx up
    // to 767 for the sliding window reads)
    __shared__ float a[2][768];
    __shared__ float ob[2][256];

    const int tid = threadIdx.x;

    // frame data is 1024 contiguous floats: (ch0,ch1) interleaved along t.
    // float2 alignment: offset = 2*(bc*20000+start) floats -> always 8B aligned.
    const float2* src = (const float2*)(in + (size_t)2 * ((size_t)bc * T_LEN + start));

    #pragma unroll
    for (int j = 0; j < 4; ++j) {
        int i = tid + 128 * j;                       // 0..511
        float2 v = src[i];
        float w = 0.5f - 0.5f * cosf((float)(6.283185307179586 / LEN_FRAME) * (float)i);
        float a0 = v.x * w;
        float a1 = v.y * w;
        a[0][i] = a0;
        a[1][i] = a1;
        if (i < 256) { a[0][i + 512] = a0; a[1][i + 512] = a1; }
    }
    __syncthreads();

    const int ch = tid >> 6;   // wave id = channel
    const int l  = tid & 63;   // lane: computes lags 4l .. 4l+3

    const float4* A4 = (const float4*)&a[ch][0];     // 192 quads, 16B aligned

    float4 acc = {0.f, 0.f, 0.f, 0.f};
    float4 alo = A4[l];                               // window quad at n=0
    #pragma unroll 8
    for (int q = 0; q < 128; ++q) {
        float4 an  = A4[q];          // broadcast read (same addr all lanes)
        float4 ahi = A4[q + l + 1];  // consecutive quads across lanes
        acc.x += an.x*alo.x + an.y*alo.y + an.z*alo.z + an.w*alo.w;
        acc.y += an.x*alo.y + an.y*alo.z + an.z*alo.w + an.w*ahi.x;
        acc.z += an.x*alo.z + an.y*alo.w + an.z*ahi.x + an.w*ahi.y;
        acc.w += an.x*alo.w + an.y*ahi.x + an.z*ahi.y + an.w*ahi.z;
        alo = ahi;
    }

    // acf[0] = lane 0's acc.x for this wave/channel
    float n0  = __shfl(acc.x, 0, 64);
    float inv = (n0 == 0.0f) ? 1.0f : (1.0f / sqrtf(n0));
    float4 r;
    r.x = fmaxf(acc.x, 0.0f) * inv;
    r.y = fmaxf(acc.y, 0.0f) * inv;
    r.z = fmaxf(acc.z, 0.0f) * inv;
    r.w = fmaxf(acc.w, 0.0f) * inv;
    ((float4*)&ob[ch][0])[l] = r;
    __syncthreads();

    // channel mean + coalesced store: 64 float4 = 256 floats
    if (tid < 64) {
        const float4* o0 = (const float4*)&ob[0][0];
        const float4* o1 = (const float4*)&ob[1][0];
        float4 x0 = o0[tid];
        float4 x1 = o1[tid];
        float4 m;
        m.x = 0.5f * (x0.x + x1.x);
        m.y = 0.5f * (x0.y + x1.y);
        m.z = 0.5f * (x0.z + x1.z);
        m.w = 0.5f * (x0.w + x1.w);
        ((float4*)(out + (size_t)bid * 256))[tid] = m;
    }
}

extern "C" void kernel_launch(void* const* d_in, const int* in_sizes, int n_in,
                              void* d_out, int out_size, void* d_ws, size_t ws_size,
                              hipStream_t stream) {
    const float* in = (const float*)d_in[0];
    float* out = (float*)d_out;
    dim3 grid(NUM_BC * NUM_FRAME);   // 60000 blocks
    dim3 block(128);
    acorr_kernel<<<grid, block, 0, stream>>>(in, out);
}

// Round 2
// 464.008 us; speedup vs baseline: 2.1785x; 2.1785x over previous
//
#include <hip/hip_runtime.h>

#define NUM_FRAME 300
#define LEN_FRAME 512
#define T_LEN     20000

typedef float v4 __attribute__((ext_vector_type(4)));

#define AS 968                          // per-(frame,ch) array stride in floats; 968 % 32 == 8
#define OFFB(n) ((n) + 4 * ((n) >> 4))  // padded float offset: quad i at 4i + 4*(i>>2)

// One wave handles 2 frames x 2 channels via 16-lane groups.
// Lane (group g, l) computes lags 16l..16l+15 for (frame g>>1, ch g&1).
// Block = 128 threads = 2 waves = 4 frames.
__global__ __launch_bounds__(128) void acorr_kernel(const float* __restrict__ in,
                                                    float* __restrict__ out) {
    __shared__ float lds[8 * AS];   // 30976 B

    const int tid  = threadIdx.x;
    const int w    = tid >> 6;
    const int lane = tid & 63;

    // ---- load + Hann window: wave w stages frames blockIdx*4 + w*2 + {0,1}
    #pragma unroll
    for (int fj = 0; fj < 2; ++fj) {
        int G  = blockIdx.x * 4 + w * 2 + fj;
        int bc = G / NUM_FRAME;
        int fr = G - bc * NUM_FRAME;
        int start = (fr == NUM_FRAME - 1)
                  ? (T_LEN - LEN_FRAME)
                  : (int)((double)fr * ((double)(T_LEN - LEN_FRAME) / (double)(NUM_FRAME - 1)));
        const float2* src = (const float2*)(in + (size_t)2 * ((size_t)bc * T_LEN + start));
        float* A0 = &lds[(w * 4 + fj * 2) * AS];
        float* A1 = A0 + AS;
        #pragma unroll
        for (int it = 0; it < 8; ++it) {
            int n = lane + 64 * it;
            float2 v = src[n];
            float wd = 0.5f - 0.5f * __cosf((float)n * (6.283185307179586f / LEN_FRAME));
            float x0 = v.x * wd, x1 = v.y * wd;
            int o = OFFB(n);
            A0[o] = x0; A1[o] = x1;
            if (n < 256) {                       // circular duplicate for lags
                int o2 = OFFB(n + 512);
                A0[o2] = x0; A1[o2] = x1;
            }
        }
    }
    __syncthreads();

    const int g = lane >> 4;    // (frame g>>1, ch g&1)
    const int l = lane & 15;    // base lag = 16l
    const float* A = &lds[(w * 4 + g) * AS];

    float qb[32];               // register ring buffer: 8 quads, slot = rel_quad & 7
    float acc[16];
    #pragma unroll
    for (int m = 0; m < 16; ++m) acc[m] = 0.0f;

    // prologue: quads 4l..4l+3 -> qb[0..15]; contiguous floats at 20l..20l+15
    {
        const v4* p = (const v4*)(A + 20 * l);
        #pragma unroll
        for (int j = 0; j < 4; ++j) {
            v4 t = p[j];
            qb[4*j+0] = t[0]; qb[4*j+1] = t[1]; qb[4*j+2] = t[2]; qb[4*j+3] = t[3];
        }
    }

    const float* slide = A + 20 * l + 20;   // f(4l+4)
    const float* anp   = A;                 // f(0)

    #pragma unroll 1
    for (int trip = 0; trip < 16; ++trip) {
        #pragma unroll
        for (int s = 0; s < 8; ++s) {
            const int off = 4 * s + ((s >= 4) ? 4 : 0);   // float offset within trip
            v4 an = *(const v4*)(anp + off);      // broadcast quad q = 8*trip+s
            v4 nq = *(const v4*)(slide + off);    // sliding quad q+4l+4
            const int sb = (16 + 4 * s) & 31;
            qb[sb+0] = nq[0]; qb[sb+1] = nq[1]; qb[sb+2] = nq[2]; qb[sb+3] = nq[3];
            #pragma unroll
            for (int m = 0; m < 16; ++m) {
                #pragma unroll
                for (int i = 0; i < 4; ++i)
                    acc[m] += an[i] * qb[(4 * s + m + i) & 31];
            }
        }
        anp   += 40;   // f advances 40 floats per 8 quads
        slide += 40;
    }

    // ---- epilogue: normalize, relu, channel mean, store
    float n0  = __shfl(acc[0], g << 4, 64);           // lag-0 of this (frame,ch)
    float inv = (n0 == 0.0f) ? 1.0f : rsqrtf(n0);
    float r[16];
    #pragma unroll
    for (int m = 0; m < 16; ++m) r[m] = fmaxf(acc[m], 0.0f) * inv;

    float mean[16];
    #pragma unroll
    for (int m = 0; m < 16; ++m)
        mean[m] = 0.5f * (r[m] + __shfl_xor(r[m], 16, 64));   // partner channel

    int G = blockIdx.x * 4 + w * 2 + (g >> 1);
    const int h = (g & 1) * 8;            // even group stores first half, odd second
    float* ob = out + (size_t)G * 256 + 16 * l + h;
    v4 t0 = { mean[h+0], mean[h+1], mean[h+2], mean[h+3] };
    v4 t1 = { mean[h+4], mean[h+5], mean[h+6], mean[h+7] };
    *(v4*)(ob)     = t0;
    *(v4*)(ob + 4) = t1;
}

extern "C" void kernel_launch(void* const* d_in, const int* in_sizes, int n_in,
                              void* d_out, int out_size, void* d_ws, size_t ws_size,
                              hipStream_t stream) {
    const float* in = (const float*)d_in[0];
    float* out = (float*)d_out;
    dim3 grid(15000);    // 60000 frames / 4 per block
    dim3 block(128);
    acorr_kernel<<<grid, block, 0, stream>>>(in, out);
}

// Round 3
// 432.453 us; speedup vs baseline: 2.3374x; 1.0730x over previous
//
#include <hip/hip_runtime.h>

#define NUM_FRAME 300
#define LEN_FRAME 512
#define T_LEN     20000

typedef float v4 __attribute__((ext_vector_type(4)));

#define AS 968                          // per-(frame,ch) array stride in floats; 968 % 32 == 8
#define OFFB(n) ((n) + 4 * ((n) >> 4))  // padded offset: quad i at 4i + 4*(i>>2)

// Block = 256 threads = 4 waves, all sharing 4 (frame,ch) LDS arrays (2 frames).
// Wave w computes the partial autocorrelation over n in [128w, 128w+128).
// Within a wave: 4 groups of 16 lanes; group g = (frame g>>1, ch g&1);
// lane l computes lags 16l..16l+15. Cross-wave reduce via LDS, wave 0 stores.
__global__ __launch_bounds__(256, 4) void acorr_kernel(const float* __restrict__ in,
                                                       float* __restrict__ out) {
    __shared__ float lds[4 * AS];   // 15488 B, also reused as reduction scratch

    const int tid  = threadIdx.x;
    const int w    = tid >> 6;
    const int lane = tid & 63;

    // ---- stage 2 frames (both channels), Hann-windowed, with circular duplicate
    #pragma unroll
    for (int fj = 0; fj < 2; ++fj) {
        int G  = blockIdx.x * 2 + fj;
        int bc = G / NUM_FRAME;
        int fr = G - bc * NUM_FRAME;
        int start = (fr == NUM_FRAME - 1)
                  ? (T_LEN - LEN_FRAME)
                  : (int)((double)fr * ((double)(T_LEN - LEN_FRAME) / (double)(NUM_FRAME - 1)));
        const float2* src = (const float2*)(in + (size_t)2 * ((size_t)bc * T_LEN + start));
        float* A0 = &lds[(2 * fj) * AS];
        float* A1 = A0 + AS;
        #pragma unroll
        for (int it = 0; it < 2; ++it) {
            int n = tid + 256 * it;
            float2 v = src[n];
            float wd = 0.5f - 0.5f * __cosf((float)n * (6.283185307179586f / LEN_FRAME));
            float x0 = v.x * wd, x1 = v.y * wd;
            int o = OFFB(n);
            A0[o] = x0; A1[o] = x1;
            if (n < 256) {
                int o2 = OFFB(n + 512);
                A0[o2] = x0; A1[o2] = x1;
            }
        }
    }
    __syncthreads();

    const int g = lane >> 4;
    const int l = lane & 15;
    const float* A = &lds[g * AS];

    v4 qb[8];            // register ring: slot = phi_quad & 7
    float acc[16];
    #pragma unroll
    for (int m = 0; m < 16; ++m) acc[m] = 0.0f;

    // prologue: phi-quads 0..3 = absolute quads 32w+4l.. ; padded base 160w+20l
    {
        const v4* p = (const v4*)(A + 160 * w + 20 * l);
        #pragma unroll
        for (int j = 0; j < 4; ++j) qb[j] = p[j];
    }

    #pragma unroll 1
    for (int t = 0; t < 4; ++t) {
        const float* anp = A + 160 * w + 40 * t;            // broadcast quads
        const float* sld = A + 160 * w + 40 * t + 20 * l;   // sliding window
        #pragma unroll
        for (int s = 0; s < 8; ++s) {
            const int pad = (s >= 4) ? 4 : 0;
            v4 an = *(const v4*)(anp + 4 * s + pad);
            qb[(4 + s) & 7] = *(const v4*)(sld + 20 + 4 * s + pad);  // phi-quad s+4
            #pragma unroll
            for (int m = 0; m < 16; ++m) {
                #pragma unroll
                for (int i = 0; i < 4; ++i)
                    acc[m] += an[i] * qb[((4 * s + m + i) >> 2) & 7][(m + i) & 3];
            }
        }
    }

    // ---- cross-wave reduction: waves 1..3 dump partials, wave 0 sums + stores
    __syncthreads();                       // all reads of frame arrays done
    if (w > 0) {
        float* scr = &lds[(w - 1) * 1024 + lane * 16];
        #pragma unroll
        for (int j = 0; j < 4; ++j) {
            v4 tq = { acc[4*j+0], acc[4*j+1], acc[4*j+2], acc[4*j+3] };
            *(v4*)(scr + 4 * j) = tq;
        }
    }
    __syncthreads();
    if (w == 0) {
        #pragma unroll
        for (int p = 0; p < 3; ++p) {
            const float* scr = &lds[p * 1024 + lane * 16];
            #pragma unroll
            for (int j = 0; j < 4; ++j) {
                v4 tq = *(const v4*)(scr + 4 * j);
                acc[4*j+0] += tq[0]; acc[4*j+1] += tq[1];
                acc[4*j+2] += tq[2]; acc[4*j+3] += tq[3];
            }
        }
        float n0  = __shfl(acc[0], g << 4, 64);      // lag-0 of this (frame,ch)
        float inv = (n0 == 0.0f) ? 1.0f : rsqrtf(n0);
        float r[16];
        #pragma unroll
        for (int m = 0; m < 16; ++m) r[m] = fmaxf(acc[m], 0.0f) * inv;
        float mean[16];
        #pragma unroll
        for (int m = 0; m < 16; ++m)
            mean[m] = 0.5f * (r[m] + __shfl_xor(r[m], 16, 64));  // partner channel

        int G = blockIdx.x * 2 + (g >> 1);
        const int h = (g & 1) * 8;
        float* ob = out + (size_t)G * 256 + 16 * l + h;
        v4 t0 = { mean[h+0], mean[h+1], mean[h+2], mean[h+3] };
        v4 t1 = { mean[h+4], mean[h+5], mean[h+6], mean[h+7] };
        *(v4*)(ob)     = t0;
        *(v4*)(ob + 4) = t1;
    }
}

extern "C" void kernel_launch(void* const* d_in, const int* in_sizes, int n_in,
                              void* d_out, int out_size, void* d_ws, size_t ws_size,
                              hipStream_t stream) {
    const float* in = (const float*)d_in[0];
    float* out = (float*)d_out;
    dim3 grid(30000);    // 60000 frames / 2 per block
    dim3 block(256);
    acorr_kernel<<<grid, block, 0, stream>>>(in, out);
}

// Round 4
// 168.096 us; speedup vs baseline: 6.0133x; 2.5727x over previous
//
#include <hip/hip_runtime.h>

#define NUM_FRAME 300
#define LEN_FRAME 512
#define T_LEN     20000

typedef _Float16 half8  __attribute__((ext_vector_type(8)));
typedef _Float16 half4v __attribute__((ext_vector_type(4)));
typedef float    floatx4 __attribute__((ext_vector_type(4)));
typedef unsigned int uint32;

// acf[16i+j] = C[i][j], C = A·B, A[i][k]=a[(k-16i) mod 512], B[k][j]=a[(k+j) mod 512]
// One block = 2 frames = 4 (frame,ch) pairs; wave w owns pair w (16 chained
// 16x16x32 f16 MFMAs, K=512). LDS: padded A image (b128-friendly, +8 f16 per
// 64), plus two parity-shifted B images (ds_read2_b32-friendly).
__global__ __launch_bounds__(256, 8) void acorr_mfma(const float* __restrict__ in,
                                                     float* __restrict__ out) {
    __shared__ __align__(16) _Float16 Apad[4][1152];  // a_ext[x]@ x+8*(x>>6), x in [272,1024)
    __shared__ __align__(16) _Float16 BEv[4][544];    // a_ext[0..528)
    __shared__ __align__(16) _Float16 BOd[4][544];    // a_ext[1..529) (shift-1 copy)

    const int tid = threadIdx.x;

    // ---------------- staging: window -> f16 -> three LDS images ----------------
    {
        const int fj = tid >> 7;           // frame within block
        const int m  = tid & 127;          // time-quad: times 4m..4m+3
        const int G  = blockIdx.x * 2 + fj;
        const int bc = G / NUM_FRAME;
        const int fr = G - bc * NUM_FRAME;
        const int start = (fr == NUM_FRAME - 1)
            ? (T_LEN - LEN_FRAME)
            : (int)((double)fr * ((double)(T_LEN - LEN_FRAME) / (double)(NUM_FRAME - 1)));
        const float2* src = (const float2*)(in + (size_t)2 * ((size_t)bc * T_LEN + start));

        const int x0 = 4 * m;
        float2 v0 = src[x0 + 0], v1 = src[x0 + 1], v2 = src[x0 + 2], v3 = src[x0 + 3];
        const int n5 = (x0 + 4) & 511;     // circular 5th sample (for shift-1 copy)
        float2 v4 = src[n5];

        const float k2 = 6.283185307179586f / LEN_FRAME;
        float w0 = 0.5f - 0.5f * __cosf((float)(x0 + 0) * k2);
        float w1 = 0.5f - 0.5f * __cosf((float)(x0 + 1) * k2);
        float w2 = 0.5f - 0.5f * __cosf((float)(x0 + 2) * k2);
        float w3 = 0.5f - 0.5f * __cosf((float)(x0 + 3) * k2);
        float w4 = 0.5f - 0.5f * __cosf((float)n5 * k2);

        #pragma unroll
        for (int c = 0; c < 2; ++c) {
            float s0 = c ? v0.y : v0.x, s1 = c ? v1.y : v1.x;
            float s2 = c ? v2.y : v2.x, s3 = c ? v3.y : v3.x;
            float s4 = c ? v4.y : v4.x;
            _Float16 h0 = (_Float16)(s0 * w0), h1 = (_Float16)(s1 * w1);
            _Float16 h2 = (_Float16)(s2 * w2), h3 = (_Float16)(s3 * w3);
            _Float16 h4 = (_Float16)(s4 * w4);
            const int p = fj * 2 + c;
            half4v qa = {h0, h1, h2, h3};
            half4v qb = {h1, h2, h3, h4};
            *(half4v*)&Apad[p][x0 + 512 + 8 * ((x0 + 512) >> 6)] = qa;   // ext [512,1024)
            if (x0 >= 272)
                *(half4v*)&Apad[p][x0 + 8 * (x0 >> 6)] = qa;             // ext [272,512)
            *(half4v*)&BEv[p][x0] = qa;
            *(half4v*)&BOd[p][x0] = qb;
            if (x0 < 16) {                                               // circular tails
                *(half4v*)&BEv[p][x0 + 512] = qa;
                *(half4v*)&BOd[p][x0 + 512] = qb;
            }
        }
    }
    __syncthreads();

    // ---------------- MFMA main: wave w = pair w ----------------
    const int w    = tid >> 6;
    const int lane = tid & 63;
    const int il   = lane & 15;    // A-row i (lag-hi) / B-col j (lag-lo)
    const int q    = lane >> 4;

    // A fragment base: ext x0A = 512 + 8q - 16*i; padded addr pA(x)=x+8*(x>>6).
    const int x0A = 512 + 8 * q - 16 * il;                 // [272, 536]
    const int pA0 = x0A + 8 * (x0A >> 6);
    const int pAo = pA0 + 32 + (((x0A & 63) >= 32) ? 8 : 0);
    const char* aE = (const char*)&Apad[w][0] + 2 * pA0;   // even K-steps, +144B/u
    const char* aO = (const char*)&Apad[w][0] + 2 * pAo;   // odd  K-steps, +144B/u

    // B fragment base: start s = 8q + j (+32 per K-step); odd j uses shift-1 copy.
    const int s0 = 8 * q + il;
    const char* bB = (il & 1) ? (const char*)&BOd[w][0] + 2 * (s0 - 1)
                              : (const char*)&BEv[w][0] + 2 * s0;

    floatx4 acc = {0.f, 0.f, 0.f, 0.f};
    #pragma unroll
    for (int u = 0; u < 8; ++u) {
        half8 a0 = *(const half8*)(aE + 144 * u);
        uint4 bw0;
        bw0.x = *(const uint32*)(bB + 128 * u + 0);
        bw0.y = *(const uint32*)(bB + 128 * u + 4);
        bw0.z = *(const uint32*)(bB + 128 * u + 8);
        bw0.w = *(const uint32*)(bB + 128 * u + 12);
        acc = __builtin_amdgcn_mfma_f32_16x16x32_f16(a0, __builtin_bit_cast(half8, bw0), acc, 0, 0, 0);

        half8 a1 = *(const half8*)(aO + 144 * u);
        uint4 bw1;
        bw1.x = *(const uint32*)(bB + 128 * u + 64);
        bw1.y = *(const uint32*)(bB + 128 * u + 68);
        bw1.z = *(const uint32*)(bB + 128 * u + 72);
        bw1.w = *(const uint32*)(bB + 128 * u + 76);
        acc = __builtin_amdgcn_mfma_f32_16x16x32_f16(a1, __builtin_bit_cast(half8, bw1), acc, 0, 0, 0);
    }

    // ---------------- epilogue: relu, 1/sqrt(acf0), channel mean, store ----------------
    // C/D layout: col j = lane&15, row i = q*4 + reg  ->  lag = 16*(q*4+reg) + j.
    float n0  = __shfl(acc[0], 0, 64);                 // lag 0 lives in lane 0, reg 0
    float n0r = fmaxf(n0, 0.f);
    float inv = (n0r == 0.f) ? 1.f : rsqrtf(n0r);
    float r0 = fmaxf(acc[0], 0.f) * inv;
    float r1 = fmaxf(acc[1], 0.f) * inv;
    float r2 = fmaxf(acc[2], 0.f) * inv;
    float r3 = fmaxf(acc[3], 0.f) * inv;

    __syncthreads();                                   // main-loop LDS reads done
    float* scr = (float*)&Apad[0][0];
    const int f   = w >> 1;
    const int idx = f * 256 + q * 64 + il;
    if (w & 1) {                                       // ch1 -> scratch
        scr[idx +  0] = r0; scr[idx + 16] = r1;
        scr[idx + 32] = r2; scr[idx + 48] = r3;
    }
    __syncthreads();
    if (!(w & 1)) {                                    // ch0: mean + store
        const int G = blockIdx.x * 2 + f;
        float* ob = out + (size_t)G * 256 + q * 64 + il;
        ob[ 0] = 0.5f * (r0 + scr[idx +  0]);
        ob[16] = 0.5f * (r1 + scr[idx + 16]);
        ob[32] = 0.5f * (r2 + scr[idx + 32]);
        ob[48] = 0.5f * (r3 + scr[idx + 48]);
    }
}

extern "C" void kernel_launch(void* const* d_in, const int* in_sizes, int n_in,
                              void* d_out, int out_size, void* d_ws, size_t ws_size,
                              hipStream_t stream) {
    const float* in = (const float*)d_in[0];
    float* out = (float*)d_out;
    dim3 grid(30000);    // 60000 frames / 2 per block
    dim3 block(256);
    acorr_mfma<<<grid, block, 0, stream>>>(in, out);
}